// Round 2
// baseline (548.110 us; speedup 1.0000x reference)
//
#include <hip/hip_runtime.h>
#include <math.h>

#define B 2
#define M 1024
#define V 300
#define C 128
#define HID 128
#define BIN 256
#define H 384
#define W 512
#define QIN (C + 7)   // 135
#define G 4           // seeds per block

// ---------------------------------------------------------------------------
// Kernel 1: anchor MLP  a[v,:]=relu(vd@Wa1+ba1)@Wa2+ba2  -> a_ws (VxHID) and
//           aT_ws (HIDxV);  bias[v]=(relu(vd@Wb1+bb1)@Wb2+bb2)[0].
// One block per view, 128 threads.
// ---------------------------------------------------------------------------
__global__ __launch_bounds__(HID) void anchor_kernel(
    const float* __restrict__ view_dirs,
    const float* __restrict__ Wa1, const float* __restrict__ ba1,
    const float* __restrict__ Wa2, const float* __restrict__ ba2,
    const float* __restrict__ Wb1, const float* __restrict__ bb1,
    const float* __restrict__ Wb2, const float* __restrict__ bb2,
    float* __restrict__ a_out, float* __restrict__ aT_out,
    float* __restrict__ bias_out) {
  const int v = blockIdx.x;
  const int t = threadIdx.x;
  __shared__ float h1[HID];

  const float vd0 = view_dirs[v * 3 + 0];
  const float vd1 = view_dirs[v * 3 + 1];
  const float vd2 = view_dirs[v * 3 + 2];

  float h = vd0 * Wa1[0 * HID + t] + vd1 * Wa1[1 * HID + t] + vd2 * Wa1[2 * HID + t] + ba1[t];
  h1[t] = fmaxf(h, 0.0f);

  // bias head: wave 0 (lanes 0..63) shuffle-reduce
  if (t < 64) {
    float x = vd0 * Wb1[0 * 64 + t] + vd1 * Wb1[1 * 64 + t] + vd2 * Wb1[2 * 64 + t] + bb1[t];
    x = fmaxf(x, 0.0f) * Wb2[t];
#pragma unroll
    for (int o = 32; o > 0; o >>= 1) x += __shfl_down(x, o, 64);
    if (t == 0) bias_out[v] = x + bb2[0];
  }
  __syncthreads();

  float acc = ba2[t];
#pragma unroll 8
  for (int k = 0; k < HID; ++k) acc += h1[k] * Wa2[k * HID + t];
  a_out[v * HID + t] = acc;
  aT_out[(size_t)t * V + v] = acc;
}

// ---------------------------------------------------------------------------
// Kernel 2: G=4 seeds per block, 128 threads.
// Round-2 change: the scattered depth_prob entropy gather (8 loads/thread,
// each a lone 4B in a distinct HBM line — the measured-invariant floor) and
// the depth_map neighborhood loads are ISSUED at kernel top into registers,
// and consumed only after the Wq1 partial (rows 0..127) has run. The random
// gather's memory time now overlaps the MLP weight streaming + FMA instead
// of serializing ahead of it (T14 async-stage pattern; reg loads survive
// __syncthreads).
// ---------------------------------------------------------------------------
__global__ __launch_bounds__(128) void seed_kernel(
    const float* __restrict__ seed, const int* __restrict__ token_sel_idx,
    const float* __restrict__ Kmat, const float* __restrict__ depth_map,
    const float* __restrict__ depth_prob, const float* __restrict__ view_dirs,
    const float* __restrict__ Wq1, const float* __restrict__ bq1,
    const float* __restrict__ Wq2, const float* __restrict__ bq2,
    const float* __restrict__ Wr1, const float* __restrict__ br1,
    const float* __restrict__ Wr2, const float* __restrict__ br2,
    const float* __restrict__ a_ws, const float* __restrict__ aT_ws,
    const float* __restrict__ bias_ws,
    float* __restrict__ out_view_score, float* __restrict__ out_top_inds,
    float* __restrict__ out_top_xyz, float* __restrict__ out_rot,
    float* __restrict__ out_res) {
  const int s0 = blockIdx.x * G;        // global seed base
  const int b = s0 >> 10;               // / M
  const int m0 = s0 & (M - 1);          // % M  (M=1024, G|M so same b for all 4)
  const int t = threadIdx.x;
  const int lane = t & 63;
  const int wv = t >> 6;

  __shared__ __align__(16) float qin_s[G][136];   // 135 + pad
  __shared__ __align__(16) float hs[G][HID];
  __shared__ __align__(16) float qs[G][HID];
  __shared__ __align__(16) float sum_s[G][HID];
  __shared__ float ered[G][2];
  __shared__ float wbv[G][2];
  __shared__ int   wbi[G][2];
  __shared__ int   sbest[G];
  __shared__ int   sidx[G];

  if (t < G) sidx[t] = token_sel_idx[b * M + m0 + t];

  // ---- seed features: issued first (oldest outstanding) ----
  const float4 sv = *(const float4*)&seed[((size_t)b * C + t) * M + m0];
  __syncthreads();   // publish sidx

  // ---- ISSUE: entropy gather loads (consumed after Wq1 partial) ----
  float pe[2 * G];
  {
    const size_t HW = (size_t)H * W;
#pragma unroll
    for (int g = 0; g < G; ++g) {
      const float* dp = depth_prob + (size_t)b * BIN * HW + sidx[g];
      pe[2 * g + 0] = dp[(size_t)(2 * t + 0) * HW];
      pe[2 * g + 1] = dp[(size_t)(2 * t + 1) * HW];
    }
  }

  // ---- ISSUE: t<G depth_map neighborhood loads (consumed after entropy) ----
  float zl = 0.f, zr = 0.f, zu = 0.f, zd = 0.f;
  int w_r = 0, h_r = 0, wc_r = 0, hc_r = 0;
  if (t < G) {
    const int idx = sidx[t];
    w_r = idx % W;
    h_r = idx / W;
    hc_r = min(max(h_r, 1), H - 2);
    wc_r = min(max(w_r, 1), W - 2);
    const float* dm = depth_map + (size_t)b * H * W;
    zl = dm[hc_r * W + (wc_r - 1)];
    zr = dm[hc_r * W + (wc_r + 1)];
    zu = dm[(hc_r - 1) * W + wc_r];
    zd = dm[(hc_r + 1) * W + wc_r];
  }

  // ---- stage seed features into LDS ----
  qin_s[0][t] = sv.x; qin_s[1][t] = sv.y; qin_s[2][t] = sv.z; qin_s[3][t] = sv.w;
  if (t < G) qin_s[t][135] = 0.0f;
  __syncthreads();

  // ---- q MLP layer 1 PARTIAL (rows 0..127): overlaps the in-flight gather ----
  float acc[G];
  {
    const float b1 = bq1[t];
#pragma unroll
    for (int g = 0; g < G; ++g) acc[g] = b1;
    for (int i0 = 0; i0 < 128; i0 += 4) {
      const float w0 = Wq1[(i0 + 0) * HID + t];
      const float w1 = Wq1[(i0 + 1) * HID + t];
      const float w2 = Wq1[(i0 + 2) * HID + t];
      const float w3 = Wq1[(i0 + 3) * HID + t];
#pragma unroll
      for (int g = 0; g < G; ++g) {
        const float4 qv = *(const float4*)&qin_s[g][i0];
        acc[g] += qv.x * w0 + qv.y * w1 + qv.z * w2 + qv.w * w3;
      }
    }
  }

  // ---- CONSUME entropy regs: logf + wave shuffle reduce ----
  {
    float e[G];
#pragma unroll
    for (int g = 0; g < G; ++g) {
      const float p0 = fmaxf(pe[2 * g + 0], 1e-8f);
      const float p1 = fmaxf(pe[2 * g + 1], 1e-8f);
      e[g] = p0 * logf(p0) + p1 * logf(p1);
    }
#pragma unroll
    for (int o = 32; o > 0; o >>= 1) {
#pragma unroll
      for (int g = 0; g < G; ++g) e[g] += __shfl_down(e[g], o, 64);
    }
    if (lane == 0) {
#pragma unroll
      for (int g = 0; g < G; ++g) ered[g][wv] = e[g];
    }
  }
  __syncthreads();

  // ---- threads 0..3: per-seed uncertainty, normal, ray -> qin_s[g][128..134] ----
  if (t < G) {
    const int g = t;
    float uncert = (-(ered[g][0] + ered[g][1])) / 5.5451774444795623f;  // log(256)
    uncert = fminf(fmaxf(uncert, 0.0f), 1.0f);

    const float fx = Kmat[b * 9 + 0], fy = Kmat[b * 9 + 4];
    const float cx = Kmat[b * 9 + 2], cy = Kmat[b * 9 + 5];
    const int w = w_r, h = h_r, hc = hc_r, wc = wc_r;

    const float dxx = (wc + 1 - cx) / fx * zr - (wc - 1 - cx) / fx * zl;
    const float dxy = (hc - cy) / fy * zr - (hc - cy) / fy * zl;
    const float dxz = zr - zl;
    const float dyx = (wc - cx) / fx * zd - (wc - cx) / fx * zu;
    const float dyy = (hc + 1 - cy) / fy * zd - (hc - 1 - cy) / fy * zu;
    const float dyz = zd - zu;

    float nx = dxy * dyz - dxz * dyy;
    float ny = dxz * dyx - dxx * dyz;
    float nz = dxx * dyy - dxy * dyx;
    const float nn = fmaxf(sqrtf(nx * nx + ny * ny + nz * nz), 1e-6f);
    const float sc = (1.0f - uncert) / nn;

    const float rx = ((float)w - cx) / fx;
    const float ry = ((float)h - cy) / fy;
    const float rn = fmaxf(sqrtf(rx * rx + ry * ry + 1.0f), 1e-12f);

    qin_s[g][128] = rx / rn;
    qin_s[g][129] = ry / rn;
    qin_s[g][130] = 1.0f / rn;
    qin_s[g][131] = nx * sc;
    qin_s[g][132] = ny * sc;
    qin_s[g][133] = nz * sc;
    qin_s[g][134] = uncert;
  }
  __syncthreads();

  // ---- q MLP layer 1 TAIL (rows 128..134) + relu ----
  {
#pragma unroll
    for (int i = 128; i < 135; ++i) {
      const float wv_ = Wq1[i * HID + t];
#pragma unroll
      for (int g = 0; g < G; ++g) acc[g] += qin_s[g][i] * wv_;
    }
#pragma unroll
    for (int g = 0; g < G; ++g) hs[g][t] = fmaxf(acc[g], 0.0f);
  }
  __syncthreads();

  // ---- q MLP layer 2 ----
  {
    const float b2 = bq2[t];
#pragma unroll
    for (int g = 0; g < G; ++g) acc[g] = b2;
    for (int k0 = 0; k0 < HID; k0 += 4) {
      const float w0 = Wq2[(k0 + 0) * HID + t];
      const float w1 = Wq2[(k0 + 1) * HID + t];
      const float w2 = Wq2[(k0 + 2) * HID + t];
      const float w3 = Wq2[(k0 + 3) * HID + t];
#pragma unroll
      for (int g = 0; g < G; ++g) {
        const float4 hv = *(const float4*)&hs[g][k0];
        acc[g] += hv.x * w0 + hv.y * w1 + hv.z * w2 + hv.w * w3;
      }
    }
#pragma unroll
    for (int g = 0; g < G; ++g) qs[g][t] = fmaxf(acc[g], 0.0f);
  }
  __syncthreads();

  // ---- logits vs all V anchors: 12 anchor loads -> 48 FMAs per chunk ----
  const int col2 = 256 + (t < 44 ? t : 43);
  float d0[G], d1[G], d2[G];
#pragma unroll
  for (int g = 0; g < G; ++g) { d0[g] = 0.0f; d1[g] = 0.0f; d2[g] = 0.0f; }
  for (int k0 = 0; k0 < HID; k0 += 4) {
    const float* r0 = aT_ws + (size_t)(k0 + 0) * V;
    const float* r1 = aT_ws + (size_t)(k0 + 1) * V;
    const float* r2 = aT_ws + (size_t)(k0 + 2) * V;
    const float* r3 = aT_ws + (size_t)(k0 + 3) * V;
    const float a00 = r0[t], a01 = r0[t + 128], a02 = r0[col2];
    const float a10 = r1[t], a11 = r1[t + 128], a12 = r1[col2];
    const float a20 = r2[t], a21 = r2[t + 128], a22 = r2[col2];
    const float a30 = r3[t], a31 = r3[t + 128], a32 = r3[col2];
#pragma unroll
    for (int g = 0; g < G; ++g) {
      const float4 qv = *(const float4*)&qs[g][k0];
      d0[g] += qv.x * a00 + qv.y * a10 + qv.z * a20 + qv.w * a30;
      d1[g] += qv.x * a01 + qv.y * a11 + qv.z * a21 + qv.w * a31;
      d2[g] += qv.x * a02 + qv.y * a12 + qv.z * a22 + qv.w * a32;
    }
  }

  const float rsq = 0.08838834764831845f;  // 1/sqrt(128)
  const float bw0 = bias_ws[t];
  const float bw1 = bias_ws[t + 128];
  const float bw2 = bias_ws[col2];
  float bv[G]; int bi[G];
#pragma unroll
  for (int g = 0; g < G; ++g) {
    const float sc0 = 1.0f / (1.0f + expf(-(d0[g] * rsq + bw0)));
    const float sc1 = 1.0f / (1.0f + expf(-(d1[g] * rsq + bw1)));
    const float sc2 = 1.0f / (1.0f + expf(-(d2[g] * rsq + bw2)));

    float* vs_out = out_view_score + (size_t)(b * M + m0 + g) * V;
    vs_out[t] = sc0;
    vs_out[t + 128] = sc1;
    if (t < 44) vs_out[t + 256] = sc2;

    // per-thread best in ascending-v order (first-index tie break)
    bv[g] = sc0; bi[g] = t;
    if (sc1 > bv[g]) { bv[g] = sc1; bi[g] = t + 128; }
    if (t < 44 && sc2 > bv[g]) { bv[g] = sc2; bi[g] = t + 256; }
  }
#pragma unroll
  for (int o = 32; o > 0; o >>= 1) {
#pragma unroll
    for (int g = 0; g < G; ++g) {
      const float ov = __shfl_down(bv[g], o, 64);
      const int oi = __shfl_down(bi[g], o, 64);
      if (ov > bv[g] || (ov == bv[g] && oi < bi[g])) { bv[g] = ov; bi[g] = oi; }
    }
  }
  if (lane == 0) {
#pragma unroll
    for (int g = 0; g < G; ++g) { wbv[g][wv] = bv[g]; wbi[g][wv] = bi[g]; }
  }
  __syncthreads();

  // ---- threads 0..3: per-seed top-1, xyz, rot ----
  if (t < G) {
    const int g = t;
    float fbv = wbv[g][0]; int fbi = wbi[g][0];
    if (wbv[g][1] > fbv || (wbv[g][1] == fbv && wbi[g][1] < fbi)) { fbv = wbv[g][1]; fbi = wbi[g][1]; }
    sbest[g] = fbi;

    const int bm = b * M + m0 + g;
    out_top_inds[bm] = (float)fbi;
    const float vx = view_dirs[fbi * 3 + 0];
    const float vy = view_dirs[fbi * 3 + 1];
    const float vz = view_dirs[fbi * 3 + 2];
    out_top_xyz[(size_t)bm * 3 + 0] = vx;
    out_top_xyz[(size_t)bm * 3 + 1] = vy;
    out_top_xyz[(size_t)bm * 3 + 2] = vz;

    float ax0 = -vx, ax1 = -vy, ax2 = -vz;
    float ay0 = vy, ay1 = -vx, ay2 = 0.0f;
    const float nyn = sqrtf(ay0 * ay0 + ay1 * ay1);
    if (nyn < 1e-8f) {
      ay0 = 0.0f; ay1 = 1.0f; ay2 = 0.0f;
    } else {
      const float d = fmaxf(nyn, 1e-8f);
      ay0 /= d; ay1 /= d;
    }
    const float an = fmaxf(sqrtf(ax0 * ax0 + ax1 * ax1 + ax2 * ax2), 1e-8f);
    ax0 /= an; ax1 /= an; ax2 /= an;
    const float az0 = ax1 * ay2 - ax2 * ay1;
    const float az1 = ax2 * ay0 - ax0 * ay2;
    const float az2 = ax0 * ay1 - ax1 * ay0;
    float* R = out_rot + (size_t)bm * 9;
    R[0] = ax0; R[1] = ay0; R[2] = az0;
    R[3] = ax1; R[4] = ay1; R[5] = az1;
    R[6] = ax2; R[7] = ay2; R[8] = az2;
  }
  __syncthreads();

  // ---- residual MLP: sum = q + a[best] staged once ----
#pragma unroll
  for (int g = 0; g < G; ++g) sum_s[g][t] = qs[g][t] + a_ws[sbest[g] * HID + t];
  __syncthreads();

  {
    const float b1 = br1[t];
#pragma unroll
    for (int g = 0; g < G; ++g) acc[g] = b1;
    for (int k0 = 0; k0 < HID; k0 += 4) {
      const float w0 = Wr1[(k0 + 0) * HID + t];
      const float w1 = Wr1[(k0 + 1) * HID + t];
      const float w2 = Wr1[(k0 + 2) * HID + t];
      const float w3 = Wr1[(k0 + 3) * HID + t];
#pragma unroll
      for (int g = 0; g < G; ++g) {
        const float4 sv2 = *(const float4*)&sum_s[g][k0];
        acc[g] += sv2.x * w0 + sv2.y * w1 + sv2.z * w2 + sv2.w * w3;
      }
    }
#pragma unroll
    for (int g = 0; g < G; ++g) hs[g][t] = fmaxf(acc[g], 0.0f);
  }
  __syncthreads();

  {
    const float b2 = br2[t];
#pragma unroll
    for (int g = 0; g < G; ++g) acc[g] = b2;
    for (int k0 = 0; k0 < HID; k0 += 4) {
      const float w0 = Wr2[(k0 + 0) * HID + t];
      const float w1 = Wr2[(k0 + 1) * HID + t];
      const float w2 = Wr2[(k0 + 2) * HID + t];
      const float w3 = Wr2[(k0 + 3) * HID + t];
#pragma unroll
      for (int g = 0; g < G; ++g) {
        const float4 hv = *(const float4*)&hs[g][k0];
        acc[g] += hv.x * w0 + hv.y * w1 + hv.z * w2 + hv.w * w3;
      }
    }
    // coalesced float4 store across m
    float4 o;
    o.x = acc[0]; o.y = acc[1]; o.z = acc[2]; o.w = acc[3];
    *(float4*)&out_res[((size_t)b * C + t) * M + m0] = o;
  }
}

// ---------------------------------------------------------------------------
extern "C" void kernel_launch(void* const* d_in, const int* in_sizes, int n_in,
                              void* d_out, int out_size, void* d_ws, size_t ws_size,
                              hipStream_t stream) {
  const float* seed  = (const float*)d_in[0];
  const int*   tok   = (const int*)d_in[1];
  const float* Km    = (const float*)d_in[2];
  const float* dmap  = (const float*)d_in[3];
  const float* dprob = (const float*)d_in[4];
  const float* vdirs = (const float*)d_in[5];
  const float* Wq1 = (const float*)d_in[6];  const float* bq1 = (const float*)d_in[7];
  const float* Wq2 = (const float*)d_in[8];  const float* bq2 = (const float*)d_in[9];
  const float* Wa1 = (const float*)d_in[10]; const float* ba1 = (const float*)d_in[11];
  const float* Wa2 = (const float*)d_in[12]; const float* ba2 = (const float*)d_in[13];
  const float* Wb1 = (const float*)d_in[14]; const float* bb1 = (const float*)d_in[15];
  const float* Wb2 = (const float*)d_in[16]; const float* bb2 = (const float*)d_in[17];
  const float* Wr1 = (const float*)d_in[18]; const float* br1 = (const float*)d_in[19];
  const float* Wr2 = (const float*)d_in[20]; const float* br2 = (const float*)d_in[21];

  float* out = (float*)d_out;
  float* vs  = out;                                  // view_score (B,M,V)
  float* ti  = vs + (size_t)B * M * V;               // top_inds  (B,M)
  float* tx  = ti + (size_t)B * M;                   // top_xyz   (B,M,3)
  float* rot = tx + (size_t)B * M * 3;               // rot       (B,M,3,3)
  float* rf  = rot + (size_t)B * M * 9;              // res_feat  (B,C,M)

  float* a_ws    = (float*)d_ws;                     // V*HID
  float* aT_ws   = a_ws + (size_t)V * HID;           // HID*V
  float* bias_ws = aT_ws + (size_t)HID * V;          // V

  anchor_kernel<<<V, HID, 0, stream>>>(vdirs, Wa1, ba1, Wa2, ba2, Wb1, bb1, Wb2, bb2,
                                       a_ws, aT_ws, bias_ws);
  seed_kernel<<<(B * M) / G, 128, 0, stream>>>(seed, tok, Km, dmap, dprob, vdirs,
                                               Wq1, bq1, Wq2, bq2, Wr1, br1, Wr2, br2,
                                               a_ws, aT_ws, bias_ws, vs, ti, tx, rot, rf);
}

// Round 3
// 543.997 us; speedup vs baseline: 1.0076x; 1.0076x over previous
//
#include <hip/hip_runtime.h>
#include <math.h>

#define B 2
#define M 1024
#define V 300
#define C 128
#define HID 128
#define BIN 256
#define H 384
#define W 512
#define QIN (C + 7)   // 135
#define G 4           // seeds per block (seed_kernel)

// ---------------------------------------------------------------------------
// Kernel 1 (fused prep): blocks [0, B*M) do the depth_prob entropy gather at
// MAX TLP (one seed per block, one bin per thread, 8192 waves total — the
// scattered 64B-line reads are throughput-bound, not latency-bound) plus the
// per-seed normal/ray/uncert tail features -> qtail_ws[bm][8].
// Blocks [B*M, B*M+V) run the anchor MLP (independent work, rides the same
// launch) -> a_ws, aT_ws, bias_ws.
// ---------------------------------------------------------------------------
__global__ __launch_bounds__(256) void prep_kernel(
    const int* __restrict__ token_sel_idx, const float* __restrict__ Kmat,
    const float* __restrict__ depth_map, const float* __restrict__ depth_prob,
    const float* __restrict__ view_dirs,
    const float* __restrict__ Wa1, const float* __restrict__ ba1,
    const float* __restrict__ Wa2, const float* __restrict__ ba2,
    const float* __restrict__ Wb1, const float* __restrict__ bb1,
    const float* __restrict__ Wb2, const float* __restrict__ bb2,
    float* __restrict__ a_out, float* __restrict__ aT_out,
    float* __restrict__ bias_out, float* __restrict__ qtail) {
  const int t = threadIdx.x;

  if (blockIdx.x < B * M) {
    // ================= entropy + geometry tail for one seed =================
    const int bm = blockIdx.x;
    const int b = bm >> 10;
    const int lane = t & 63;
    const int wv = t >> 6;
    __shared__ float ered[4];
    __shared__ int sidx_s;
    if (t == 0) sidx_s = token_sel_idx[bm];
    __syncthreads();
    const int idx = sidx_s;

    // issue thread-0 depth_map neighborhood early (overlaps the gather)
    float zl = 0.f, zr = 0.f, zu = 0.f, zd = 0.f;
    int w_r = 0, h_r = 0, wc_r = 0, hc_r = 0;
    if (t == 0) {
      w_r = idx % W;
      h_r = idx / W;
      hc_r = min(max(h_r, 1), H - 2);
      wc_r = min(max(w_r, 1), W - 2);
      const float* dm = depth_map + (size_t)b * H * W;
      zl = dm[hc_r * W + (wc_r - 1)];
      zr = dm[hc_r * W + (wc_r + 1)];
      zu = dm[(hc_r - 1) * W + wc_r];
      zd = dm[(hc_r + 1) * W + wc_r];
    }

    // one bin per thread: the scattered load
    const size_t HW = (size_t)H * W;
    float p = depth_prob[(size_t)b * BIN * HW + (size_t)t * HW + idx];
    p = fmaxf(p, 1e-8f);
    float e = p * logf(p);
#pragma unroll
    for (int o = 32; o > 0; o >>= 1) e += __shfl_down(e, o, 64);
    if (lane == 0) ered[wv] = e;
    __syncthreads();

    if (t == 0) {
      float uncert = (-(ered[0] + ered[1] + ered[2] + ered[3])) / 5.5451774444795623f;
      uncert = fminf(fmaxf(uncert, 0.0f), 1.0f);

      const float fx = Kmat[b * 9 + 0], fy = Kmat[b * 9 + 4];
      const float cx = Kmat[b * 9 + 2], cy = Kmat[b * 9 + 5];
      const int w = w_r, h = h_r, hc = hc_r, wc = wc_r;

      const float dxx = (wc + 1 - cx) / fx * zr - (wc - 1 - cx) / fx * zl;
      const float dxy = (hc - cy) / fy * zr - (hc - cy) / fy * zl;
      const float dxz = zr - zl;
      const float dyx = (wc - cx) / fx * zd - (wc - cx) / fx * zu;
      const float dyy = (hc + 1 - cy) / fy * zd - (hc - 1 - cy) / fy * zu;
      const float dyz = zd - zu;

      float nx = dxy * dyz - dxz * dyy;
      float ny = dxz * dyx - dxx * dyz;
      float nz = dxx * dyy - dxy * dyx;
      const float nn = fmaxf(sqrtf(nx * nx + ny * ny + nz * nz), 1e-6f);
      const float sc = (1.0f - uncert) / nn;

      const float rx = ((float)w - cx) / fx;
      const float ry = ((float)h - cy) / fy;
      const float rn = fmaxf(sqrtf(rx * rx + ry * ry + 1.0f), 1e-12f);

      float* q = qtail + (size_t)bm * 8;
      q[0] = rx / rn;
      q[1] = ry / rn;
      q[2] = 1.0f / rn;
      q[3] = nx * sc;
      q[4] = ny * sc;
      q[5] = nz * sc;
      q[6] = uncert;
      q[7] = 0.0f;
    }
  } else {
    // ========================== anchor MLP for one view =====================
    const int v = blockIdx.x - B * M;
    __shared__ float h1[HID];

    if (t < HID) {
      const float vd0 = view_dirs[v * 3 + 0];
      const float vd1 = view_dirs[v * 3 + 1];
      const float vd2 = view_dirs[v * 3 + 2];

      float h = vd0 * Wa1[0 * HID + t] + vd1 * Wa1[1 * HID + t] + vd2 * Wa1[2 * HID + t] + ba1[t];
      h1[t] = fmaxf(h, 0.0f);

      if (t < 64) {
        float x = vd0 * Wb1[0 * 64 + t] + vd1 * Wb1[1 * 64 + t] + vd2 * Wb1[2 * 64 + t] + bb1[t];
        x = fmaxf(x, 0.0f) * Wb2[t];
#pragma unroll
        for (int o = 32; o > 0; o >>= 1) x += __shfl_down(x, o, 64);
        if (t == 0) bias_out[v] = x + bb2[0];
      }
    }
    __syncthreads();

    if (t < HID) {
      float acc = ba2[t];
#pragma unroll 8
      for (int k = 0; k < HID; ++k) acc += h1[k] * Wa2[k * HID + t];
      a_out[v * HID + t] = acc;
      aT_out[(size_t)t * V + v] = acc;
    }
  }
}

// ---------------------------------------------------------------------------
// Kernel 2: G=4 seeds per block, 128 threads. Pure compute + L2 weight
// streaming now — the scattered gather lives in prep_kernel. Seed features
// read directly from (B,C,M) as float4 across m; qin tail from qtail_ws.
// ---------------------------------------------------------------------------
__global__ __launch_bounds__(128) void seed_kernel(
    const float* __restrict__ seed, const float* __restrict__ qtail,
    const float* __restrict__ view_dirs,
    const float* __restrict__ Wq1, const float* __restrict__ bq1,
    const float* __restrict__ Wq2, const float* __restrict__ bq2,
    const float* __restrict__ Wr1, const float* __restrict__ br1,
    const float* __restrict__ Wr2, const float* __restrict__ br2,
    const float* __restrict__ a_ws, const float* __restrict__ aT_ws,
    const float* __restrict__ bias_ws,
    float* __restrict__ out_view_score, float* __restrict__ out_top_inds,
    float* __restrict__ out_top_xyz, float* __restrict__ out_rot,
    float* __restrict__ out_res) {
  const int s0 = blockIdx.x * G;        // global seed base (== bm of seed 0)
  const int b = s0 >> 10;
  const int m0 = s0 & (M - 1);
  const int t = threadIdx.x;
  const int lane = t & 63;
  const int wv = t >> 6;

  __shared__ __align__(16) float qin_s[G][136];   // row = 544B (16B-aligned)
  __shared__ __align__(16) float hs[G][HID];
  __shared__ __align__(16) float qs[G][HID];
  __shared__ __align__(16) float sum_s[G][HID];
  __shared__ float wbv[G][2];
  __shared__ int   wbi[G][2];
  __shared__ int   sbest[G];

  // ---- seed features (coalesced float4 across m) + qin tail from ws ----
  const float4 sv = *(const float4*)&seed[((size_t)b * C + t) * M + m0];
  if (t < 2 * G) {
    const int g = t >> 1, half = t & 1;
    ((float4*)&qin_s[g][128])[half] =
        ((const float4*)(qtail + (size_t)(s0 + g) * 8))[half];
  }
  qin_s[0][t] = sv.x; qin_s[1][t] = sv.y; qin_s[2][t] = sv.z; qin_s[3][t] = sv.w;
  __syncthreads();

  // ---- q MLP layer 1 (135 rows) ----
  float acc[G];
  {
    const float b1 = bq1[t];
#pragma unroll
    for (int g = 0; g < G; ++g) acc[g] = b1;
    for (int i0 = 0; i0 < 132; i0 += 4) {
      const float w0 = Wq1[(i0 + 0) * HID + t];
      const float w1 = Wq1[(i0 + 1) * HID + t];
      const float w2 = Wq1[(i0 + 2) * HID + t];
      const float w3 = Wq1[(i0 + 3) * HID + t];
#pragma unroll
      for (int g = 0; g < G; ++g) {
        const float4 qv = *(const float4*)&qin_s[g][i0];
        acc[g] += qv.x * w0 + qv.y * w1 + qv.z * w2 + qv.w * w3;
      }
    }
    {  // tail rows 132..134
      const float w0 = Wq1[132 * HID + t];
      const float w1 = Wq1[133 * HID + t];
      const float w2 = Wq1[134 * HID + t];
#pragma unroll
      for (int g = 0; g < G; ++g) {
        const float4 qv = *(const float4*)&qin_s[g][132];
        acc[g] += qv.x * w0 + qv.y * w1 + qv.z * w2;
      }
    }
#pragma unroll
    for (int g = 0; g < G; ++g) hs[g][t] = fmaxf(acc[g], 0.0f);
  }
  __syncthreads();

  // ---- q MLP layer 2 ----
  {
    const float b2 = bq2[t];
#pragma unroll
    for (int g = 0; g < G; ++g) acc[g] = b2;
    for (int k0 = 0; k0 < HID; k0 += 4) {
      const float w0 = Wq2[(k0 + 0) * HID + t];
      const float w1 = Wq2[(k0 + 1) * HID + t];
      const float w2 = Wq2[(k0 + 2) * HID + t];
      const float w3 = Wq2[(k0 + 3) * HID + t];
#pragma unroll
      for (int g = 0; g < G; ++g) {
        const float4 hv = *(const float4*)&hs[g][k0];
        acc[g] += hv.x * w0 + hv.y * w1 + hv.z * w2 + hv.w * w3;
      }
    }
#pragma unroll
    for (int g = 0; g < G; ++g) qs[g][t] = fmaxf(acc[g], 0.0f);
  }
  __syncthreads();

  // ---- logits vs all V anchors (12 anchor loads -> 48 FMAs per chunk) ----
  const int col2 = 256 + (t < 44 ? t : 43);
  float d0[G], d1[G], d2[G];
#pragma unroll
  for (int g = 0; g < G; ++g) { d0[g] = 0.0f; d1[g] = 0.0f; d2[g] = 0.0f; }
  for (int k0 = 0; k0 < HID; k0 += 4) {
    const float* r0 = aT_ws + (size_t)(k0 + 0) * V;
    const float* r1 = aT_ws + (size_t)(k0 + 1) * V;
    const float* r2 = aT_ws + (size_t)(k0 + 2) * V;
    const float* r3 = aT_ws + (size_t)(k0 + 3) * V;
    const float a00 = r0[t], a01 = r0[t + 128], a02 = r0[col2];
    const float a10 = r1[t], a11 = r1[t + 128], a12 = r1[col2];
    const float a20 = r2[t], a21 = r2[t + 128], a22 = r2[col2];
    const float a30 = r3[t], a31 = r3[t + 128], a32 = r3[col2];
#pragma unroll
    for (int g = 0; g < G; ++g) {
      const float4 qv = *(const float4*)&qs[g][k0];
      d0[g] += qv.x * a00 + qv.y * a10 + qv.z * a20 + qv.w * a30;
      d1[g] += qv.x * a01 + qv.y * a11 + qv.z * a21 + qv.w * a31;
      d2[g] += qv.x * a02 + qv.y * a12 + qv.z * a22 + qv.w * a32;
    }
  }

  const float rsq = 0.08838834764831845f;  // 1/sqrt(128)
  const float bw0 = bias_ws[t];
  const float bw1 = bias_ws[t + 128];
  const float bw2 = bias_ws[col2];
  float bv[G]; int bi[G];
#pragma unroll
  for (int g = 0; g < G; ++g) {
    const float sc0 = 1.0f / (1.0f + expf(-(d0[g] * rsq + bw0)));
    const float sc1 = 1.0f / (1.0f + expf(-(d1[g] * rsq + bw1)));
    const float sc2 = 1.0f / (1.0f + expf(-(d2[g] * rsq + bw2)));

    float* vs_out = out_view_score + (size_t)(s0 + g) * V;
    vs_out[t] = sc0;
    vs_out[t + 128] = sc1;
    if (t < 44) vs_out[t + 256] = sc2;

    bv[g] = sc0; bi[g] = t;
    if (sc1 > bv[g]) { bv[g] = sc1; bi[g] = t + 128; }
    if (t < 44 && sc2 > bv[g]) { bv[g] = sc2; bi[g] = t + 256; }
  }
#pragma unroll
  for (int o = 32; o > 0; o >>= 1) {
#pragma unroll
    for (int g = 0; g < G; ++g) {
      const float ov = __shfl_down(bv[g], o, 64);
      const int oi = __shfl_down(bi[g], o, 64);
      if (ov > bv[g] || (ov == bv[g] && oi < bi[g])) { bv[g] = ov; bi[g] = oi; }
    }
  }
  if (lane == 0) {
#pragma unroll
    for (int g = 0; g < G; ++g) { wbv[g][wv] = bv[g]; wbi[g][wv] = bi[g]; }
  }
  __syncthreads();

  // ---- threads 0..3: per-seed top-1, xyz, rot ----
  if (t < G) {
    const int g = t;
    float fbv = wbv[g][0]; int fbi = wbi[g][0];
    if (wbv[g][1] > fbv || (wbv[g][1] == fbv && wbi[g][1] < fbi)) { fbv = wbv[g][1]; fbi = wbi[g][1]; }
    sbest[g] = fbi;

    const int bm = s0 + g;
    out_top_inds[bm] = (float)fbi;
    const float vx = view_dirs[fbi * 3 + 0];
    const float vy = view_dirs[fbi * 3 + 1];
    const float vz = view_dirs[fbi * 3 + 2];
    out_top_xyz[(size_t)bm * 3 + 0] = vx;
    out_top_xyz[(size_t)bm * 3 + 1] = vy;
    out_top_xyz[(size_t)bm * 3 + 2] = vz;

    float ax0 = -vx, ax1 = -vy, ax2 = -vz;
    float ay0 = vy, ay1 = -vx, ay2 = 0.0f;
    const float nyn = sqrtf(ay0 * ay0 + ay1 * ay1);
    if (nyn < 1e-8f) {
      ay0 = 0.0f; ay1 = 1.0f; ay2 = 0.0f;
    } else {
      const float d = fmaxf(nyn, 1e-8f);
      ay0 /= d; ay1 /= d;
    }
    const float an = fmaxf(sqrtf(ax0 * ax0 + ax1 * ax1 + ax2 * ax2), 1e-8f);
    ax0 /= an; ax1 /= an; ax2 /= an;
    const float az0 = ax1 * ay2 - ax2 * ay1;
    const float az1 = ax2 * ay0 - ax0 * ay2;
    const float az2 = ax0 * ay1 - ax1 * ay0;
    float* R = out_rot + (size_t)bm * 9;
    R[0] = ax0; R[1] = ay0; R[2] = az0;
    R[3] = ax1; R[4] = ay1; R[5] = az1;
    R[6] = ax2; R[7] = ay2; R[8] = az2;
  }
  __syncthreads();

  // ---- residual MLP: sum = q + a[best] staged once ----
#pragma unroll
  for (int g = 0; g < G; ++g) sum_s[g][t] = qs[g][t] + a_ws[sbest[g] * HID + t];
  __syncthreads();

  {
    const float b1 = br1[t];
#pragma unroll
    for (int g = 0; g < G; ++g) acc[g] = b1;
    for (int k0 = 0; k0 < HID; k0 += 4) {
      const float w0 = Wr1[(k0 + 0) * HID + t];
      const float w1 = Wr1[(k0 + 1) * HID + t];
      const float w2 = Wr1[(k0 + 2) * HID + t];
      const float w3 = Wr1[(k0 + 3) * HID + t];
#pragma unroll
      for (int g = 0; g < G; ++g) {
        const float4 sv2 = *(const float4*)&sum_s[g][k0];
        acc[g] += sv2.x * w0 + sv2.y * w1 + sv2.z * w2 + sv2.w * w3;
      }
    }
#pragma unroll
    for (int g = 0; g < G; ++g) hs[g][t] = fmaxf(acc[g], 0.0f);
  }
  __syncthreads();

  {
    const float b2 = br2[t];
#pragma unroll
    for (int g = 0; g < G; ++g) acc[g] = b2;
    for (int k0 = 0; k0 < HID; k0 += 4) {
      const float w0 = Wr2[(k0 + 0) * HID + t];
      const float w1 = Wr2[(k0 + 1) * HID + t];
      const float w2 = Wr2[(k0 + 2) * HID + t];
      const float w3 = Wr2[(k0 + 3) * HID + t];
#pragma unroll
      for (int g = 0; g < G; ++g) {
        const float4 hv = *(const float4*)&hs[g][k0];
        acc[g] += hv.x * w0 + hv.y * w1 + hv.z * w2 + hv.w * w3;
      }
    }
    float4 o;
    o.x = acc[0]; o.y = acc[1]; o.z = acc[2]; o.w = acc[3];
    *(float4*)&out_res[((size_t)b * C + t) * M + m0] = o;
  }
}

// ---------------------------------------------------------------------------
extern "C" void kernel_launch(void* const* d_in, const int* in_sizes, int n_in,
                              void* d_out, int out_size, void* d_ws, size_t ws_size,
                              hipStream_t stream) {
  const float* seed  = (const float*)d_in[0];
  const int*   tok   = (const int*)d_in[1];
  const float* Km    = (const float*)d_in[2];
  const float* dmap  = (const float*)d_in[3];
  const float* dprob = (const float*)d_in[4];
  const float* vdirs = (const float*)d_in[5];
  const float* Wq1 = (const float*)d_in[6];  const float* bq1 = (const float*)d_in[7];
  const float* Wq2 = (const float*)d_in[8];  const float* bq2 = (const float*)d_in[9];
  const float* Wa1 = (const float*)d_in[10]; const float* ba1 = (const float*)d_in[11];
  const float* Wa2 = (const float*)d_in[12]; const float* ba2 = (const float*)d_in[13];
  const float* Wb1 = (const float*)d_in[14]; const float* bb1 = (const float*)d_in[15];
  const float* Wb2 = (const float*)d_in[16]; const float* bb2 = (const float*)d_in[17];
  const float* Wr1 = (const float*)d_in[18]; const float* br1 = (const float*)d_in[19];
  const float* Wr2 = (const float*)d_in[20]; const float* br2 = (const float*)d_in[21];

  float* out = (float*)d_out;
  float* vs  = out;                                  // view_score (B,M,V)
  float* ti  = vs + (size_t)B * M * V;               // top_inds  (B,M)
  float* tx  = ti + (size_t)B * M;                   // top_xyz   (B,M,3)
  float* rot = tx + (size_t)B * M * 3;               // rot       (B,M,3,3)
  float* rf  = rot + (size_t)B * M * 9;              // res_feat  (B,C,M)

  float* a_ws    = (float*)d_ws;                     // V*HID
  float* aT_ws   = a_ws + (size_t)V * HID;           // HID*V
  float* bias_ws = aT_ws + (size_t)HID * V;          // V
  float* qtail   = bias_ws + V;                      // B*M*8

  prep_kernel<<<B * M + V, 256, 0, stream>>>(tok, Km, dmap, dprob, vdirs,
                                             Wa1, ba1, Wa2, ba2, Wb1, bb1, Wb2, bb2,
                                             a_ws, aT_ws, bias_ws, qtail);
  seed_kernel<<<(B * M) / G, 128, 0, stream>>>(seed, qtail, vdirs,
                                               Wq1, bq1, Wq2, bq2, Wr1, br1, Wr2, br2,
                                               a_ws, aT_ws, bias_ws, vs, ti, tx, rot, rf);
}